// Round 7
// baseline (205.860 us; speedup 1.0000x reference)
//
#include <hip/hip_runtime.h>
#include <hip/hip_bf16.h>

typedef __attribute__((ext_vector_type(8))) __bf16 bf16x8;
typedef __attribute__((ext_vector_type(4))) float f32x4;

#define B_M 256
#define K_D 512
#define N_C 100000
#define TM 64                         /* wave tile M */
#define TN 64                         /* wave tile N */
#define NT_N ((N_C + TN - 1) / TN)    /* 1563 N-tiles */
#define N_TILES (4 * NT_N)            /* 6252 wave-tiles (4 M-tiles x 1563) */
#define NBLK2 ((N_TILES + 7) / 8)     /* 782 blocks of 8 waves */

__device__ __forceinline__ unsigned short f2bf(float x) {
  unsigned int u = __float_as_uint(x);
  u += 0x7fffu + ((u >> 16) & 1u);          // round-to-nearest-even
  return (unsigned short)(u >> 16);
}

__device__ __forceinline__ bf16x8 pack8(float4 a, float4 b) {
  union { unsigned short us[8]; bf16x8 v; } u;
  u.us[0] = f2bf(a.x); u.us[1] = f2bf(a.y); u.us[2] = f2bf(a.z); u.us[3] = f2bf(a.w);
  u.us[4] = f2bf(b.x); u.us[5] = f2bf(b.y); u.us[6] = f2bf(b.z); u.us[7] = f2bf(b.w);
  return u.v;
}

// ---------------- kernel 1: row-normalize emb -> bf16 ff (linear layout) ----------------
__global__ __launch_bounds__(256) void norm_kernel(const float* __restrict__ emb,
                                                   unsigned short* __restrict__ ff) {
  const int row = blockIdx.x;
  const int t = threadIdx.x;
  float a = emb[row * K_D + t];
  float b = emb[row * K_D + t + 256];
  float ss = a * a + b * b;
  #pragma unroll
  for (int o = 32; o > 0; o >>= 1) ss += __shfl_down(ss, o, 64);
  __shared__ float red[4];
  const int wid = t >> 6, lane = t & 63;
  if (lane == 0) red[wid] = ss;
  __syncthreads();
  float tot = red[0] + red[1] + red[2] + red[3];
  float rn = 1.0f / fmaxf(sqrtf(tot), 1e-12f);
  ff[row * K_D + t]       = f2bf(a * rn);
  ff[row * K_D + t + 256] = f2bf(b * rn);
}

// ---------------- kernel 2: wave-independent GEMM + fused circle-loss ----------------
// 8 waves/block, each wave owns an independent 64x64 output tile. NO barriers in the
// K-loop: A frags stream from L2-resident ff, B frags stream from W (coalesced 128B
// per column per step, every line fully used), cvt f32->bf16 in-register, 16 MFMA/step,
// 16 steps fully unrolled -> compiler software-pipelines the 192 loads like a pure
// streaming kernel (the 7 TB/s fill-kernel regime). One __syncthreads pair total.
__global__ __launch_bounds__(512) void gemm_loss_kernel(const unsigned short* __restrict__ ff,
                                                        const float* __restrict__ W,
                                                        const int* __restrict__ labels,
                                                        double* __restrict__ partials) {
  __shared__ int lbl[B_M];
  __shared__ double red[16];

  const int tid = threadIdx.x;
  const int wid = tid >> 6;
  const int lane = tid & 63;
  const int l15 = lane & 15;
  const int lhi = lane >> 4;

  if (tid < B_M) lbl[tid] = labels[tid];
  __syncthreads();

  const int tile = blockIdx.x * 8 + wid;          // may be >= N_TILES for last block
  const bool live = tile < N_TILES;
  const int mt = (tile & 3) * TM;                 // 0..192
  const int nt = (tile >> 2) * TN;                // 0..99968  (garbage if !live, guarded)

  // per-frag base pointers (immediate offsets walk K)
  const unsigned short* apf[4];
  const float* wpf[4];
  bool cvalid[4];
  #pragma unroll
  for (int i = 0; i < 4; ++i) {
    int arow = mt + i * 16 + l15;                           // < 256
    apf[i] = ff + arow * K_D + lhi * 8;
    int col = nt + i * 16 + l15;
    cvalid[i] = live && (col < N_C);
    int cc = (col < N_C && live) ? col : 0;                 // clamp for safe loads
    wpf[i] = W + (long long)cc * K_D + lhi * 8;
  }

  f32x4 acc[4][4] = {};

  if (live) {
    #pragma unroll
    for (int kk = 0; kk < 16; ++kk) {
      bf16x8 afr[4], bfr[4];
      #pragma unroll
      for (int i = 0; i < 4; ++i)
        afr[i] = *reinterpret_cast<const bf16x8*>(apf[i] + kk * 32);
      #pragma unroll
      for (int i = 0; i < 4; ++i) {
        float4 lo = *reinterpret_cast<const float4*>(wpf[i] + kk * 32);
        float4 hi = *reinterpret_cast<const float4*>(wpf[i] + kk * 32 + 4);
        bfr[i] = pack8(lo, hi);
      }
      #pragma unroll
      for (int am = 0; am < 4; ++am)
        #pragma unroll
        for (int bn = 0; bn < 4; ++bn)
          acc[am][bn] = __builtin_amdgcn_mfma_f32_16x16x32_bf16(afr[am], bfr[bn], acc[am][bn], 0, 0, 0);
    }
  }

  // ---- fused epilogue: circle-loss terms ----
  float sn_local = 0.0f;
  double sp_local = 0.0;
  #pragma unroll
  for (int bn = 0; bn < 4; ++bn) {
    const int col = nt + bn * 16 + l15;
    const bool cv = cvalid[bn];
    #pragma unroll
    for (int am = 0; am < 4; ++am)
      #pragma unroll
      for (int r = 0; r < 4; ++r) {
        const int row = mt + am * 16 + lhi * 4 + r;   // C/D: col=lane&15, row=(lane>>4)*4+reg
        float v = acc[am][bn][r];
        if (cv) {
          if (col == lbl[row]) {
            double alpha = fmax(1.25 - (double)v, 0.0);     // clamp(Op - sp, 0)
            sp_local += exp(-64.0 * alpha * ((double)v - 0.75));
          } else {
            float an = fmaxf(v + 0.25f, 0.0f);              // clamp(sn + m, 0)
            sn_local += __expf(64.0f * an * (v - 0.25f));
          }
        }
      }
  }

  double sn_d = (double)sn_local;
  #pragma unroll
  for (int o = 32; o > 0; o >>= 1) {
    sn_d     += __shfl_down(sn_d, o, 64);
    sp_local += __shfl_down(sp_local, o, 64);
  }
  if (lane == 0) { red[wid] = sn_d; red[8 + wid] = sp_local; }
  __syncthreads();
  if (tid == 0) {
    double a = 0.0, b = 0.0;
    #pragma unroll
    for (int i = 0; i < 8; ++i) { a += red[i]; b += red[8 + i]; }
    partials[blockIdx.x] = a;            // sn partial
    partials[NBLK2 + blockIdx.x] = b;    // sp partial
  }
}

// ---------------- kernel 3: final reduce + log1p ----------------
__global__ __launch_bounds__(512) void finalize_kernel(const double* __restrict__ partials,
                                                       float* __restrict__ out) {
  const int t = threadIdx.x;
  double sn = 0.0, sp = 0.0;
  for (int i = t; i < NBLK2; i += 512) { sn += partials[i]; sp += partials[NBLK2 + i]; }
  #pragma unroll
  for (int o = 32; o > 0; o >>= 1) { sn += __shfl_down(sn, o, 64); sp += __shfl_down(sp, o, 64); }
  __shared__ double red[16];
  const int wid = t >> 6, lane = t & 63;
  if (lane == 0) { red[wid] = sn; red[8 + wid] = sp; }
  __syncthreads();
  if (t == 0) {
    double a = 0.0, b = 0.0;
    for (int i = 0; i < 8; ++i) { a += red[i]; b += red[8 + i]; }
    out[0] = (float)log1p(a * b);
  }
}

extern "C" void kernel_launch(void* const* d_in, const int* in_sizes, int n_in,
                              void* d_out, int out_size, void* d_ws, size_t ws_size,
                              hipStream_t stream) {
  // inputs: 0=x (unused), 1=labels (int), 2=emb (f32), 3=W (f32)
  const int*   labels = (const int*)d_in[1];
  const float* emb    = (const float*)d_in[2];
  const float* W      = (const float*)d_in[3];
  float* out = (float*)d_out;

  unsigned short* ff = (unsigned short*)d_ws;                              // 256*512*2 = 262144 B
  double* partials = (double*)((char*)d_ws + (size_t)B_M * K_D * 2);       // 2*782*8 B

  norm_kernel<<<B_M, 256, 0, stream>>>(emb, ff);
  gemm_loss_kernel<<<NBLK2, 512, 0, stream>>>(ff, W, labels, partials);
  finalize_kernel<<<1, 512, 0, stream>>>(partials, out);
}

// Round 8
// 150.407 us; speedup vs baseline: 1.3687x; 1.3687x over previous
//
#include <hip/hip_runtime.h>
#include <hip/hip_bf16.h>

typedef __attribute__((ext_vector_type(8))) __bf16 bf16x8;
typedef __attribute__((ext_vector_type(4))) float f32x4;

#define B_M 256
#define K_D 512
#define N_C 100000
#define BN 64
#define BK 64
#define NBLK ((N_C + BN - 1) / BN)   /* 1563 */

__device__ __forceinline__ unsigned short f2bf(float x) {
  unsigned int u = __float_as_uint(x);
  u += 0x7fffu + ((u >> 16) & 1u);          // round-to-nearest-even
  return (unsigned short)(u >> 16);
}

// ---------------- kernel 1: row-normalize emb -> bf16 ff ----------------
__global__ __launch_bounds__(256) void norm_kernel(const float* __restrict__ emb,
                                                   unsigned short* __restrict__ ff) {
  const int row = blockIdx.x;
  const int t = threadIdx.x;
  float a = emb[row * K_D + t];
  float b = emb[row * K_D + t + 256];
  float ss = a * a + b * b;
  #pragma unroll
  for (int o = 32; o > 0; o >>= 1) ss += __shfl_down(ss, o, 64);
  __shared__ float red[4];
  const int wid = t >> 6, lane = t & 63;
  if (lane == 0) red[wid] = ss;
  __syncthreads();
  float tot = red[0] + red[1] + red[2] + red[3];
  float rn = 1.0f / fmaxf(sqrtf(tot), 1e-12f);
  ff[row * K_D + t]       = f2bf(a * rn);
  ff[row * K_D + t + 256] = f2bf(b * rn);
}

// ---------------- kernel 2: fused GEMM + circle-loss partial reduce ----------------
// R1's proven 2-barrier structure with ONE change (T14 async-STAGE split):
// global loads for step t+1 are ISSUED right after barrier 1 of step t, so their
// latency hides under step t's ds_read+MFMA compute phase; only the reg->LDS
// writes remain in the stage phase. Same LDS layout/swizzle/barriers as R1.
__global__ __launch_bounds__(512) void gemm_loss_kernel(const unsigned short* __restrict__ ff,
                                                        const float* __restrict__ W,
                                                        const int* __restrict__ labels,
                                                        double* __restrict__ partials) {
  __shared__ __align__(16) unsigned short As[B_M * BK];  // 32 KB, XOR-swizzled
  __shared__ __align__(16) unsigned short Bs[BN * BK];   //  8 KB, XOR-swizzled
  __shared__ int lbl[B_M];
  __shared__ double red[16];

  const int tid = threadIdx.x;
  const int wid = tid >> 6;
  const int lane = tid & 63;
  const int n0 = blockIdx.x * BN;

  if (tid < B_M) lbl[tid] = labels[tid];

  f32x4 acc[2][4] = {};

  const int wrow = wid * 32;
  const int l15 = lane & 15;
  const int lhi = lane >> 4;

  // A staging geometry: 4 chunks/thread, chunk s = it*512+tid -> row=s>>3, kc=s&7
  // W staging geometry: thread -> (col, 8-float chunk)
  const int bcol = tid >> 3;              // 0..63
  const int bk8  = tid & 7;               // 0..7
  const bool valid = (n0 + bcol) < N_C;
  const float* wp = W + (long long)(n0 + bcol) * K_D + bk8 * 8;

  uint4 areg[4];
  float4 wr0 = {0.f,0.f,0.f,0.f}, wr1 = {0.f,0.f,0.f,0.f};

  // ---- prologue: load step-0 tiles into regs ----
  #pragma unroll
  for (int it = 0; it < 4; ++it) {
    int s = it * 512 + tid;
    int row = s >> 3;
    int kc  = s & 7;
    areg[it] = *reinterpret_cast<const uint4*>(ff + row * K_D + kc * 8);
  }
  if (valid) {
    wr0 = *reinterpret_cast<const float4*>(wp);
    wr1 = *reinterpret_cast<const float4*>(wp + 4);
  }

  for (int kk = 0; kk < K_D / BK; ++kk) {
    // ---- write phase: staged regs -> LDS (swizzled) ----
    #pragma unroll
    for (int it = 0; it < 4; ++it) {
      int s = it * 512 + tid;
      int row = s >> 3;
      int kc  = s & 7;
      int off = (row * 128 + kc * 16) ^ ((row & 7) << 4);
      *reinterpret_cast<uint4*>(reinterpret_cast<char*>(As) + off) = areg[it];
    }
    {
      union { unsigned short us[8]; uint4 v; } pk;
      pk.us[0] = f2bf(wr0.x); pk.us[1] = f2bf(wr0.y); pk.us[2] = f2bf(wr0.z); pk.us[3] = f2bf(wr0.w);
      pk.us[4] = f2bf(wr1.x); pk.us[5] = f2bf(wr1.y); pk.us[6] = f2bf(wr1.z); pk.us[7] = f2bf(wr1.w);
      int off = (bcol * 128 + bk8 * 16) ^ ((bcol & 7) << 4);
      *reinterpret_cast<uint4*>(reinterpret_cast<char*>(Bs) + off) = pk.v;
    }
    __syncthreads();

    // ---- issue next step's global loads (latency hides under compute below) ----
    if (kk + 1 < K_D / BK) {
      #pragma unroll
      for (int it = 0; it < 4; ++it) {
        int s = it * 512 + tid;
        int row = s >> 3;
        int kc  = s & 7;
        areg[it] = *reinterpret_cast<const uint4*>(ff + row * K_D + (kk + 1) * BK + kc * 8);
      }
      if (valid) {
        wr0 = *reinterpret_cast<const float4*>(wp + (kk + 1) * BK);
        wr1 = *reinterpret_cast<const float4*>(wp + (kk + 1) * BK + 4);
      }
    }

    // ---- compute phase: fragments + MFMA ----
    bf16x8 afr[2][2], bfr[4][2];
    #pragma unroll
    for (int fm = 0; fm < 2; ++fm)
      #pragma unroll
      for (int ks = 0; ks < 2; ++ks) {
        int row = wrow + fm * 16 + l15;
        int off = (row * 128 + ks * 64 + lhi * 16) ^ ((row & 7) << 4);
        afr[fm][ks] = *reinterpret_cast<const bf16x8*>(reinterpret_cast<const char*>(As) + off);
      }
    #pragma unroll
    for (int fn = 0; fn < 4; ++fn)
      #pragma unroll
      for (int ks = 0; ks < 2; ++ks) {
        int col = fn * 16 + l15;
        int off = (col * 128 + ks * 64 + lhi * 16) ^ ((col & 7) << 4);
        bfr[fn][ks] = *reinterpret_cast<const bf16x8*>(reinterpret_cast<const char*>(Bs) + off);
      }
    #pragma unroll
    for (int fm = 0; fm < 2; ++fm)
      #pragma unroll
      for (int fn = 0; fn < 4; ++fn)
        #pragma unroll
        for (int ks = 0; ks < 2; ++ks)
          acc[fm][fn] = __builtin_amdgcn_mfma_f32_16x16x32_bf16(afr[fm][ks], bfr[fn][ks], acc[fm][fn], 0, 0, 0);
    __syncthreads();
  }

  // ---- fused epilogue: circle-loss terms ----
  float sn_local = 0.0f;
  double sp_local = 0.0;
  #pragma unroll
  for (int fm = 0; fm < 2; ++fm)
    #pragma unroll
    for (int fn = 0; fn < 4; ++fn)
      #pragma unroll
      for (int r = 0; r < 4; ++r) {
        int row = wrow + fm * 16 + lhi * 4 + r;   // C/D: col=lane&15, row=(lane>>4)*4+reg
        int j = n0 + fn * 16 + l15;
        float v = acc[fm][fn][r];
        if (j < N_C) {
          if (j == lbl[row]) {
            double alpha = fmax(1.25 - (double)v, 0.0);     // clamp(Op - sp, 0)
            sp_local += exp(-64.0 * alpha * ((double)v - 0.75));
          } else {
            float an = fmaxf(v + 0.25f, 0.0f);              // clamp(sn + m, 0)
            sn_local += __expf(64.0f * an * (v - 0.25f));
          }
        }
      }

  double sn_d = (double)sn_local;
  #pragma unroll
  for (int o = 32; o > 0; o >>= 1) {
    sn_d     += __shfl_down(sn_d, o, 64);
    sp_local += __shfl_down(sp_local, o, 64);
  }
  if (lane == 0) { red[wid] = sn_d; red[8 + wid] = sp_local; }
  __syncthreads();
  if (tid == 0) {
    double a = 0.0, b = 0.0;
    #pragma unroll
    for (int i = 0; i < 8; ++i) { a += red[i]; b += red[8 + i]; }
    partials[blockIdx.x] = a;          // sn partial
    partials[NBLK + blockIdx.x] = b;   // sp partial
  }
}

// ---------------- kernel 3: final reduce + log1p ----------------
__global__ __launch_bounds__(512) void finalize_kernel(const double* __restrict__ partials,
                                                       float* __restrict__ out) {
  const int t = threadIdx.x;
  double sn = 0.0, sp = 0.0;
  for (int i = t; i < NBLK; i += 512) { sn += partials[i]; sp += partials[NBLK + i]; }
  #pragma unroll
  for (int o = 32; o > 0; o >>= 1) { sn += __shfl_down(sn, o, 64); sp += __shfl_down(sp, o, 64); }
  __shared__ double red[16];
  const int wid = t >> 6, lane = t & 63;
  if (lane == 0) { red[wid] = sn; red[8 + wid] = sp; }
  __syncthreads();
  if (t == 0) {
    double a = 0.0, b = 0.0;
    for (int i = 0; i < 8; ++i) { a += red[i]; b += red[8 + i]; }
    out[0] = (float)log1p(a * b);
  }
}

extern "C" void kernel_launch(void* const* d_in, const int* in_sizes, int n_in,
                              void* d_out, int out_size, void* d_ws, size_t ws_size,
                              hipStream_t stream) {
  // inputs: 0=x (unused), 1=labels (int), 2=emb (f32), 3=W (f32)
  const int*   labels = (const int*)d_in[1];
  const float* emb    = (const float*)d_in[2];
  const float* W      = (const float*)d_in[3];
  float* out = (float*)d_out;

  unsigned short* ff = (unsigned short*)d_ws;                              // 256*512*2 = 262144 B
  double* partials = (double*)((char*)d_ws + (size_t)B_M * K_D * 2);       // 2*1563*8 B

  norm_kernel<<<B_M, 256, 0, stream>>>(emb, ff);
  gemm_loss_kernel<<<NBLK, 512, 0, stream>>>(ff, W, labels, partials);
  finalize_kernel<<<1, 512, 0, stream>>>(partials, out);
}